// Round 19
// baseline (119.742 us; speedup 1.0000x reference)
//
#include <hip/hip_runtime.h>
#include <math.h>

#define HH 768
#define NHEADS 12
#define HDIM 64
#define SEQ 2048
#define NB 2
#define L2E 1.44269504088896f

typedef __attribute__((ext_vector_type(8))) short s8v;
typedef __attribute__((ext_vector_type(4))) short s4v;
typedef __attribute__((ext_vector_type(4))) float f4v;

static __device__ inline short f2bf(float f) {
    union { float f; unsigned u; } v; v.f = f;
    unsigned r = v.u + 0x7fff + ((v.u >> 16) & 1);   // RNE
    return (short)(r >> 16);
}

#if __has_builtin(__builtin_amdgcn_exp2f)
#define EXP2(x) __builtin_amdgcn_exp2f(x)
#else
#define EXP2(x) __expf((x) * 0.6931471805599453f)
#endif

__device__ __forceinline__ unsigned cvt_pk_bf16(float a, float b) {
    unsigned r;
    asm("v_cvt_pk_bf16_f32 %0, %1, %2" : "=v"(r) : "v"(a), "v"(b));
    return r;
}

__device__ __forceinline__ void gld16(const void* g, void* l) {
    __builtin_amdgcn_global_load_lds(
        (const __attribute__((address_space(1))) void*)g,
        (__attribute__((address_space(3))) void*)l, 16, 0, 0);
}

// k-position permutation within each 32-group (shared by V^T layout, mask
// layout, and the PV MFMA slot order): pos = 8*((k>>2)&3) + 4*((k>>4)&1) + (k&3)
__device__ __forceinline__ int kperm(int k) {
    return (k & ~31) | (((k >> 2) & 3) << 3) | (((k >> 4) & 1) << 2) | (k & 3);
}

// ---------------------------------------------------------------------------
// fp32 -> bf16 conversion: X (4096x768) and the 4 weight matrices (768x768).
// ---------------------------------------------------------------------------
#define XV8   393216
#define WV8   73728
__global__ __launch_bounds__(256)
void cvt_kernel(const float* __restrict__ X, short* __restrict__ Xb,
                const float* __restrict__ W0, short* __restrict__ W0b,
                const float* __restrict__ W1, short* __restrict__ W1b,
                const float* __restrict__ W2, short* __restrict__ W2b,
                const float* __restrict__ W3, short* __restrict__ W3b)
{
    int gid = blockIdx.x * 256 + threadIdx.x;
    const float* src; short* dst; size_t off;
    if      (gid < XV8)            { src = X;  dst = Xb;  off = gid; }
    else if (gid < XV8 + WV8)      { src = W0; dst = W0b; off = gid - XV8; }
    else if (gid < XV8 + 2*WV8)    { src = W1; dst = W1b; off = gid - XV8 - WV8; }
    else if (gid < XV8 + 3*WV8)    { src = W2; dst = W2b; off = gid - XV8 - 2*WV8; }
    else if (gid < XV8 + 4*WV8)    { src = W3; dst = W3b; off = gid - XV8 - 3*WV8; }
    else return;
    off *= 8;
    float4 a = *(const float4*)(src + off);
    float4 b = *(const float4*)(src + off + 4);
    s8v o;
    o[0] = f2bf(a.x); o[1] = f2bf(a.y); o[2] = f2bf(a.z); o[3] = f2bf(a.w);
    o[4] = f2bf(b.x); o[5] = f2bf(b.y); o[6] = f2bf(b.z); o[7] = f2bf(b.w);
    *(s8v*)(dst + off) = o;
}

// ---------------------------------------------------------------------------
// MFMA GEMM, 128x128 tile, BK=32, 4 waves (2x2, 64x64 each => 16 MFMA/iter).
// 2-buffer LDS (32 KB), counted vmcnt(4) + raw s_barrier. Full residency:
// QKV 576 blocks (2.25/CU, cap 4), proj 192 blocks. Bijective XCD swizzle.
// LDS 128-byte-line layout (r15 conflict-free): line = 2 rows of 32 bf16;
// 16B slot s = (row&1)*4 + (g ^ (line&3)); staging linear, src pre-swizzled.
// EPI 0: fused QKV. seg 0/1 -> bf16 [B,NH,S,HD] (Q pre-scaled 0.125*log2e);
//        seg 2 -> bf16 V^T [B,NH,HD,S], kperm columns.
// EPI 1: out-proj -> fp32 + bias + residual.
// ---------------------------------------------------------------------------
#define NKT (HH/32)
template<int EPI>
__global__ __launch_bounds__(256)
void gemm_mfma(const short* __restrict__ A,
               const short* __restrict__ Wq, const short* __restrict__ Wk,
               const short* __restrict__ Wv,
               const float* __restrict__ bq, const float* __restrict__ bk,
               const float* __restrict__ bv,
               short* __restrict__ Qo, short* __restrict__ Ko, short* __restrict__ Vo,
               const float* __restrict__ Xres, float* __restrict__ Fo)
{
    __shared__ __align__(16) short As[2*128*32];   // 16 KB
    __shared__ __align__(16) short Bs[2*128*32];   // 16 KB

    const int tid  = threadIdx.x;
    const int w    = tid >> 6;
    const int lane = tid & 63;
    const int g    = lane >> 4;
    const int r    = lane & 15;
    const int wr   = w >> 1;      // m-half (64 rows)
    const int wc   = w & 1;       // n-half (64 cols)

    // bijective XCD swizzle
    const int NBX = (EPI == 0) ? 18 : 6;
    const int NXB = (EPI == 0) ? 72 : 24;
    const int wg  = (blockIdx.x & 7) * NXB + (blockIdx.x >> 3);
    const int bx  = wg % NBX;
    const int by  = wg / NBX;
    const int m0  = by * 128;

    int n0;
    int seg = 0;
    const short* Wb; const float* bias; short* outp; float scale;
    if (EPI == 0) {
        seg = bx / 6;
        n0 = (bx % 6) * 128;
        Wb   = seg == 0 ? Wq : seg == 1 ? Wk : Wv;
        bias = seg == 0 ? bq : seg == 1 ? bk : bv;
        outp = seg == 0 ? Qo : seg == 1 ? Ko : Vo;
        scale = seg == 0 ? (0.125f * L2E) : 1.0f;
    } else {
        n0 = bx * 128;
        Wb = Wq; bias = bq; outp = nullptr; scale = 1.0f;
    }

    // staging map (slot u in [0,512)): line=u>>3, us=u&7,
    // row = 2*line + (us>>2), col = 8*((us&3)^(line&3)).
    // Thread covers u=tid and u=tid+256 (= same col key, row+64).
    const int uline = tid >> 3;
    const int us    = tid & 7;
    const int srow  = 2*uline + (us >> 2);
    const int scol  = 8 * ((us & 3) ^ (uline & 3));
    const short* Asrc = A  + (size_t)(m0 + srow) * HH + scol;
    const short* Bsrc = Wb + (size_t)(n0 + srow) * HH + scol;

    #define GSTAGE(KT, DB) do { const int k0 = (KT) * 32;                      \
        gld16(Asrc + k0,           As + (DB)*4096 + w*512);                    \
        gld16(Asrc + 64*HH + k0,   As + (DB)*4096 + 2048 + w*512);             \
        gld16(Bsrc + k0,           Bs + (DB)*4096 + w*512);                    \
        gld16(Bsrc + 64*HH + k0,   Bs + (DB)*4096 + 2048 + w*512);             \
    } while (0)

    f4v acc[4][4];
    #pragma unroll
    for (int i = 0; i < 4; i++)
        #pragma unroll
        for (int j = 0; j < 4; j++) acc[i][j] = (f4v){0.f,0.f,0.f,0.f};

    // fragment read: row R -> elems (R>>1)*64 + (R&1)*32 + keyg; +mi*512/16rows
    const int keyg  = (g ^ ((r >> 1) & 3)) * 8;
    const int abase = (wr*32 + (r >> 1))*64 + (r & 1)*32 + keyg;
    const int bbase = (wc*32 + (r >> 1))*64 + (r & 1)*32 + keyg;

    #define GCOMPUTE(DB) do {                                                  \
        const short* Ab = As + (DB)*4096;                                      \
        const short* Bb = Bs + (DB)*4096;                                      \
        s8v af[4], bf[4];                                                      \
        _Pragma("unroll")                                                      \
        for (int mi = 0; mi < 4; mi++)                                         \
            af[mi] = *(const s8v*)(Ab + abase + mi*512);                       \
        _Pragma("unroll")                                                      \
        for (int ni = 0; ni < 4; ni++)                                         \
            bf[ni] = *(const s8v*)(Bb + bbase + ni*512);                       \
        __builtin_amdgcn_s_setprio(1);                                         \
        _Pragma("unroll")                                                      \
        for (int mi = 0; mi < 4; mi++)                                         \
            _Pragma("unroll")                                                  \
            for (int ni = 0; ni < 4; ni++)                                     \
                acc[mi][ni] = __builtin_amdgcn_mfma_f32_16x16x32_bf16(         \
                    af[mi], bf[ni], acc[mi][ni], 0, 0, 0);                     \
        __builtin_amdgcn_s_setprio(0);                                         \
    } while (0)

    GSTAGE(0, 0);

    for (int kt = 0; kt < NKT; ++kt) {
        if (kt + 1 < NKT) {
            GSTAGE(kt + 1, (kt + 1) & 1);
            asm volatile("s_waitcnt vmcnt(4)" ::: "memory");  // own 4 loads done
        } else {
            asm volatile("s_waitcnt vmcnt(0)" ::: "memory");
        }
        __builtin_amdgcn_s_barrier();
        GCOMPUTE(kt & 1);
        __builtin_amdgcn_s_barrier();
    }

    if (EPI == 0) {
        if (seg < 2) {
            #pragma unroll
            for (int mi = 0; mi < 4; mi++) {
                #pragma unroll
                for (int j = 0; j < 4; j++) {
                    const int m = m0 + wr*64 + mi*16 + 4*g + j;
                    const int bb = m >> 11;
                    const int s  = m & 2047;
                    #pragma unroll
                    for (int ni = 0; ni < 4; ni++) {
                        const int n = n0 + wc*64 + ni*16 + r;
                        const int h = n >> 6;
                        const int d = n & 63;
                        outp[((size_t)((bb*NHEADS + h)*SEQ) + s)*HDIM + d] =
                            f2bf((acc[mi][ni][j] + bias[n]) * scale);
                    }
                }
            }
        } else {
            // V^T direct, k-permuted columns: 4 contiguous s stay contiguous
            #pragma unroll
            for (int mi = 0; mi < 4; mi++) {
                const int m  = m0 + wr*64 + mi*16 + 4*g;   // 4-aligned
                const int bb = m >> 11;
                const int s  = m & 2047;
                const int sp = kperm(s);                   // 4-aligned too
                #pragma unroll
                for (int ni = 0; ni < 4; ni++) {
                    const int n = n0 + wc*64 + ni*16 + r;
                    const int h = n >> 6;
                    const int d = n & 63;
                    s4v pk;
                    #pragma unroll
                    for (int j = 0; j < 4; j++)
                        pk[j] = f2bf(acc[mi][ni][j] + bias[n]);
                    *(s4v*)(outp + ((size_t)((bb*NHEADS + h)*HDIM) + d)*SEQ + sp) = pk;
                }
            }
        }
    } else {
        #pragma unroll
        for (int mi = 0; mi < 4; mi++) {
            #pragma unroll
            for (int j = 0; j < 4; j++) {
                const int m = m0 + wr*64 + mi*16 + 4*g + j;
                #pragma unroll
                for (int ni = 0; ni < 4; ni++) {
                    const int n = n0 + wc*64 + ni*16 + r;
                    Fo[(size_t)m*HH + n] = acc[mi][ni][j] + bias[n] + Xres[(size_t)m*HH + n];
                }
            }
        }
    }
    #undef GSTAGE
    #undef GCOMPUTE
}

// ---------------------------------------------------------------------------
// Flash attention, bf16 MFMA, 8 waves / 512 threads, KV-parity split.
// SWAPPED QK^T (mask as MFMA C-init); PV A-fragment in-register (cvt_pk);
// l-sum via ONES-MFMA. Counted-vmcnt loop (vmcnt(2), raw barriers).
// LDS 40 KB (K 2x8K, V 2x8K, mask-f32 8K); 128B rows, conflict-free.
// ---------------------------------------------------------------------------
#define NPAIR (SEQ/64)
__global__ __launch_bounds__(512, 4)
void attn_mfma(const short* __restrict__ Q, const short* __restrict__ K,
               const short* __restrict__ VT, const float* __restrict__ mask,
               short* __restrict__ CTX)
{
    const int wgid = (blockIdx.x & 7) * 96 + (blockIdx.x >> 3);
    const int qt = wgid & 31;
    const int bh = wgid >> 5;
    const int h  = bh % NHEADS;
    const int b  = bh / NHEADS;

    const size_t hb = (size_t)(b * NHEADS + h);
    const short* Qg  = Q  + hb * SEQ * HDIM;
    const short* Kg  = K  + hb * SEQ * HDIM;
    const short* VTg = VT + hb * HDIM * SEQ;   // k-permuted columns

    __shared__ __align__(16) char lds[40960];
    char* Kbase = lds;
    char* Vbase = lds + 16384;
    float* Mf   = (float*)(lds + 32768);

    const int tid  = threadIdx.x;
    const int w    = tid >> 6;
    const int grp  = w >> 2;
    const int wq   = w & 3;
    const int lane = tid & 63;
    const int g    = lane >> 4;
    const int r    = lane & 15;
    const int q0   = qt * 64;

    const short* qrow = Qg + (size_t)(q0 + wq*16 + r) * HDIM;
    const s8v qf0 = *(const s8v*)(qrow + 8*g);
    const s8v qf1 = *(const s8v*)(qrow + 8*g + 32);

    {
        float4 mv = *(const float4*)(mask + b*SEQ + tid*4);
        f4v md;
        md[0] = (mv.x - 1.0f) * (10000.0f * L2E);
        md[1] = (mv.y - 1.0f) * (10000.0f * L2E);
        md[2] = (mv.z - 1.0f) * (10000.0f * L2E);
        md[3] = (mv.w - 1.0f) * (10000.0f * L2E);
        *(f4v*)(Mf + kperm(tid*4)) = md;
    }

    f4v acc[4];
    #pragma unroll
    for (int t = 0; t < 4; t++) acc[t] = (f4v){0.f, 0.f, 0.f, 0.f};
    f4v accl = (f4v){0.f, 0.f, 0.f, 0.f};
    const s8v ones = (s8v){0x3F80, 0x3F80, 0x3F80, 0x3F80,
                           0x3F80, 0x3F80, 0x3F80, 0x3F80};

    const int srow = lane >> 3;
    const int scol = 8 * ((lane & 7) ^ srow);

    #define STAGE(PT, DB) do {                                                 \
        const int pk0 = (PT) * 64;                                             \
        char* kd = Kbase + (DB)*8192 + w*1024;                                 \
        gld16(Kg + (size_t)(pk0 + 8*w + srow)*HDIM + scol, kd);                \
        char* vd = Vbase + (DB)*8192 + w*1024;                                 \
        gld16(VTg + (size_t)(8*w + srow)*SEQ + pk0 + scol, vd);                \
    } while (0)

    STAGE(0, 0);
    __syncthreads();

    for (int pt = 0; pt < NPAIR; ++pt) {
        const int db = pt & 1;
        if (pt + 1 < NPAIR) {
            STAGE(pt + 1, db ^ 1);
            asm volatile("s_waitcnt vmcnt(2)" ::: "memory");
        } else {
            asm volatile("s_waitcnt vmcnt(0)" ::: "memory");
        }
        __builtin_amdgcn_s_barrier();

        const char* Kc = Kbase + db*8192 + grp*4096;
        const char* Vc = Vbase + db*8192;

        const float* mrow = Mf + pt*64 + grp*32 + 8*g;
        f4v z0 = *(const f4v*)(mrow);
        f4v z1 = *(const f4v*)(mrow + 4);

        __builtin_amdgcn_s_setprio(1);
        {
            const int sw = (r & 7) << 4;
            const char* kb0 = Kc + r * 128;
            const char* kb1 = Kc + (16 + r) * 128;
            s8v ka0 = *(const s8v*)(kb0 + ((16*g)      ^ sw));
            s8v ka1 = *(const s8v*)(kb0 + ((16*g + 64) ^ sw));
            s8v kc0 = *(const s8v*)(kb1 + ((16*g)      ^ sw));
            s8v kc1 = *(const s8v*)(kb1 + ((16*g + 64) ^ sw));
            z0 = __builtin_amdgcn_mfma_f32_16x16x32_bf16(ka0, qf0, z0, 0, 0, 0);
            z0 = __builtin_amdgcn_mfma_f32_16x16x32_bf16(ka1, qf1, z0, 0, 0, 0);
            z1 = __builtin_amdgcn_mfma_f32_16x16x32_bf16(kc0, qf0, z1, 0, 0, 0);
            z1 = __builtin_amdgcn_mfma_f32_16x16x32_bf16(kc1, qf1, z1, 0, 0, 0);
        }
        __builtin_amdgcn_s_setprio(0);

        #pragma unroll
        for (int i = 0; i < 4; i++) {
            z0[i] = EXP2(z0[i]);
            z1[i] = EXP2(z1[i]);
        }

        union { unsigned u[4]; s8v v; } pfu;
        pfu.u[0] = cvt_pk_bf16(z0[0], z0[1]);
        pfu.u[1] = cvt_pk_bf16(z0[2], z0[3]);
        pfu.u[2] = cvt_pk_bf16(z1[0], z1[1]);
        pfu.u[3] = cvt_pk_bf16(z1[2], z1[3]);
        const s8v pf = pfu.v;

        accl = __builtin_amdgcn_mfma_f32_16x16x32_bf16(pf, ones, accl, 0, 0, 0);

        __builtin_amdgcn_s_setprio(1);
        #pragma unroll
        for (int t4 = 0; t4 < 4; t4++) {
            const int vrow = 16*t4 + r;
            s8v vf = *(const s8v*)(Vc + vrow*128 + ((16*(4*grp + g)) ^ ((r & 7) << 4)));
            acc[t4] = __builtin_amdgcn_mfma_f32_16x16x32_bf16(pf, vf, acc[t4], 0, 0, 0);
        }
        __builtin_amdgcn_s_setprio(0);

        __builtin_amdgcn_s_barrier();
    }

    __syncthreads();
    if (grp == 1) {
        float* mb = (float*)(lds + wq*5120 + lane*80);
        *(f4v*)(mb)      = acc[0];
        *(f4v*)(mb + 4)  = acc[1];
        *(f4v*)(mb + 8)  = acc[2];
        *(f4v*)(mb + 12) = acc[3];
        *(f4v*)(mb + 16) = accl;
    }
    __syncthreads();
    if (grp == 0) {
        const float* mb = (const float*)(lds + wq*5120 + lane*80);
        acc[0] += *(const f4v*)(mb);
        acc[1] += *(const f4v*)(mb + 4);
        acc[2] += *(const f4v*)(mb + 8);
        acc[3] += *(const f4v*)(mb + 12);
        accl   += *(const f4v*)(mb + 16);

        #pragma unroll
        for (int i = 0; i < 4; i++) {
            const float invl = 1.0f / accl[i];
            const size_t rowbase = ((size_t)(b*SEQ) + q0 + wq*16 + 4*g + i) * HH + h*HDIM;
            #pragma unroll
            for (int t4 = 0; t4 < 4; t4++)
                CTX[rowbase + 16*t4 + r] = f2bf(acc[t4][i] * invl);
        }
    }
    #undef STAGE
}

// ---------------------------------------------------------------------------
// In-place LayerNorm over rows of 768.
// ---------------------------------------------------------------------------
__global__ __launch_bounds__(256)
void ln_kernel(float* __restrict__ y, const float* __restrict__ gamma,
               const float* __restrict__ beta)
{
    const int row = blockIdx.x;
    float* p = y + (size_t)row * HH;
    const int tid = threadIdx.x;

    float v[3];
    float s = 0.f, ss = 0.f;
    #pragma unroll
    for (int i = 0; i < 3; i++) {
        float x = p[tid + i*256];
        v[i] = x;
        s += x;
        ss += x * x;
    }
    #pragma unroll
    for (int off = 32; off > 0; off >>= 1) {
        s  += __shfl_down(s,  off);
        ss += __shfl_down(ss, off);
    }
    __shared__ float sbuf[4], ssbuf[4];
    __shared__ float mu_s, rstd_s;
    const int wave = tid >> 6;
    if ((tid & 63) == 0) { sbuf[wave] = s; ssbuf[wave] = ss; }
    __syncthreads();
    if (tid == 0) {
        float S  = sbuf[0] + sbuf[1] + sbuf[2] + sbuf[3];
        float SS = ssbuf[0] + ssbuf[1] + ssbuf[2] + ssbuf[3];
        float mu = S * (1.0f / HH);
        float var = SS * (1.0f / HH) - mu * mu;
        mu_s = mu;
        rstd_s = rsqrtf(var + 1e-5f);
    }
    __syncthreads();
    const float mu = mu_s, rstd = rstd_s;
    #pragma unroll
    for (int i = 0; i < 3; i++) {
        const int c = tid + i*256;
        p[c] = (v[i] - mu) * rstd * gamma[c] + beta[c];
    }
}

// ---------------------------------------------------------------------------
extern "C" void kernel_launch(void* const* d_in, const int* in_sizes, int n_in,
                              void* d_out, int out_size, void* d_ws, size_t ws_size,
                              hipStream_t stream)
{
    const float* x     = (const float*)d_in[0];
    const float* mask  = (const float*)d_in[1];
    const float* Wq    = (const float*)d_in[2];
    const float* bq    = (const float*)d_in[3];
    const float* Wk    = (const float*)d_in[4];
    const float* bk    = (const float*)d_in[5];
    const float* Wv    = (const float*)d_in[6];
    const float* bv    = (const float*)d_in[7];
    const float* Wo    = (const float*)d_in[8];
    const float* bo    = (const float*)d_in[9];
    const float* gamma = (const float*)d_in[10];
    const float* beta  = (const float*)d_in[11];

    const size_t PER = (size_t)NB * NHEADS * SEQ * HDIM;
    const size_t WSZ = (size_t)HH * HH;
    short* wsS  = (short*)d_ws;
    short* Xb   = wsS;          // dead after QKV GEMM -> reused as CTXb
    short* Wqb  = wsS + PER;
    short* Wkb  = Wqb + WSZ;
    short* Wvb  = Wkb + WSZ;
    short* Wob  = Wvb + WSZ;
    short* Qb   = Wob + WSZ;
    short* Kb   = Qb + PER;
    short* VTb  = Kb + PER;     // k-permuted V^T written directly by the GEMM
    short* CTXb = Xb;
    float* out  = (float*)d_out;

    cvt_kernel<<<2688, 256, 0, stream>>>(x, Xb, Wq, Wqb, Wk, Wkb, Wv, Wvb, Wo, Wob);

    gemm_mfma<0><<<576, 256, 0, stream>>>(
        Xb, Wqb, Wkb, Wvb, bq, bk, bv, Qb, Kb, VTb, nullptr, nullptr);

    attn_mfma<<<768, 512, 0, stream>>>(Qb, Kb, VTb, mask, CTXb);

    gemm_mfma<1><<<192, 256, 0, stream>>>(
        CTXb, Wob, nullptr, nullptr, bo, nullptr, nullptr,
        nullptr, nullptr, nullptr, x, out);

    ln_kernel<<<NB*SEQ, 256, 0, stream>>>(out, gamma, beta);
}

// Round 20
// 100.374 us; speedup vs baseline: 1.1930x; 1.1930x over previous
//
#include <hip/hip_runtime.h>
#include <math.h>

#define HH 768
#define NHEADS 12
#define HDIM 64
#define SEQ 2048
#define NB 2
#define L2E 1.44269504088896f

typedef __attribute__((ext_vector_type(8))) short s8v;
typedef __attribute__((ext_vector_type(4))) short s4v;
typedef __attribute__((ext_vector_type(4))) float f4v;

static __device__ inline short f2bf(float f) {
    union { float f; unsigned u; } v; v.f = f;
    unsigned r = v.u + 0x7fff + ((v.u >> 16) & 1);   // RNE
    return (short)(r >> 16);
}

#if __has_builtin(__builtin_amdgcn_exp2f)
#define EXP2(x) __builtin_amdgcn_exp2f(x)
#else
#define EXP2(x) __expf((x) * 0.6931471805599453f)
#endif

__device__ __forceinline__ unsigned cvt_pk_bf16(float a, float b) {
    unsigned r;
    asm("v_cvt_pk_bf16_f32 %0, %1, %2" : "=v"(r) : "v"(a), "v"(b));
    return r;
}

__device__ __forceinline__ void gld16(const void* g, void* l) {
    __builtin_amdgcn_global_load_lds(
        (const __attribute__((address_space(1))) void*)g,
        (__attribute__((address_space(3))) void*)l, 16, 0, 0);
}

// k-position permutation within each 32-group (shared by V^T layout, mask
// layout, and the PV MFMA slot order): pos = 8*((k>>2)&3) + 4*((k>>4)&1) + (k&3)
__device__ __forceinline__ int kperm(int k) {
    return (k & ~31) | (((k >> 2) & 3) << 3) | (((k >> 4) & 1) << 2) | (k & 3);
}

// ---------------------------------------------------------------------------
// fp32 -> bf16 conversion: X (4096x768) and the 4 weight matrices (768x768).
// ---------------------------------------------------------------------------
#define XV8   393216
#define WV8   73728
__global__ __launch_bounds__(256)
void cvt_kernel(const float* __restrict__ X, short* __restrict__ Xb,
                const float* __restrict__ W0, short* __restrict__ W0b,
                const float* __restrict__ W1, short* __restrict__ W1b,
                const float* __restrict__ W2, short* __restrict__ W2b,
                const float* __restrict__ W3, short* __restrict__ W3b)
{
    int gid = blockIdx.x * 256 + threadIdx.x;
    const float* src; short* dst; size_t off;
    if      (gid < XV8)            { src = X;  dst = Xb;  off = gid; }
    else if (gid < XV8 + WV8)      { src = W0; dst = W0b; off = gid - XV8; }
    else if (gid < XV8 + 2*WV8)    { src = W1; dst = W1b; off = gid - XV8 - WV8; }
    else if (gid < XV8 + 3*WV8)    { src = W2; dst = W2b; off = gid - XV8 - 2*WV8; }
    else if (gid < XV8 + 4*WV8)    { src = W3; dst = W3b; off = gid - XV8 - 3*WV8; }
    else return;
    off *= 8;
    float4 a = *(const float4*)(src + off);
    float4 b = *(const float4*)(src + off + 4);
    s8v o;
    o[0] = f2bf(a.x); o[1] = f2bf(a.y); o[2] = f2bf(a.z); o[3] = f2bf(a.w);
    o[4] = f2bf(b.x); o[5] = f2bf(b.y); o[6] = f2bf(b.z); o[7] = f2bf(b.w);
    *(s8v*)(dst + off) = o;
}

// ---------------------------------------------------------------------------
// MFMA GEMM, 64x128 tile, BK=32, 4 waves (2m x 2n, 32x64 each).
// Grid flattened 1D with bijective XCD swizzle.
// EPI 0: fused QKV (1152 blocks). seg 0/1 -> bf16 [B,NH,S,HD] (Q pre-scaled
//        by 0.125*log2e); seg 2 (V) -> bf16 V^T [B,NH,HD,S], kperm columns.
// EPI 1: out-proj (384 blocks) -> fp32 [4096,768] + bias + residual.
// ---------------------------------------------------------------------------
template<int EPI>
__global__ __launch_bounds__(256)
void gemm_mfma(const short* __restrict__ A,
               const short* __restrict__ Wq, const short* __restrict__ Wk,
               const short* __restrict__ Wv,
               const float* __restrict__ bq, const float* __restrict__ bk,
               const float* __restrict__ bv,
               short* __restrict__ Qo, short* __restrict__ Ko, short* __restrict__ Vo,
               const float* __restrict__ Xres, float* __restrict__ Fo)
{
    __shared__ __align__(16) short As[64*32];    // 4 KB
    __shared__ __align__(16) short Bs[128*32];   // 8 KB

    const int tid  = threadIdx.x;
    const int w    = tid >> 6;
    const int lane = tid & 63;
    const int g    = lane >> 4;
    const int r    = lane & 15;
    const int wr   = w >> 1;      // m-half (32 rows)
    const int wc   = w & 1;       // n-half (64 cols)

    // bijective XCD swizzle: NXB = blocks/XCD
    const int NBX = (EPI == 0) ? 18 : 6;
    const int NXB = (EPI == 0) ? 144 : 48;
    const int wg  = (blockIdx.x & 7) * NXB + (blockIdx.x >> 3);
    const int bx  = wg % NBX;
    const int by  = wg / NBX;
    const int m0  = by * 64;

    int n0;
    int seg = 0;
    const short* Wb; const float* bias; short* outp; float scale;
    if (EPI == 0) {
        seg = bx / 6;
        n0 = (bx % 6) * 128;
        Wb   = seg == 0 ? Wq : seg == 1 ? Wk : Wv;
        bias = seg == 0 ? bq : seg == 1 ? bk : bv;
        outp = seg == 0 ? Qo : seg == 1 ? Ko : Vo;
        scale = seg == 0 ? (0.125f * L2E) : 1.0f;
    } else {
        n0 = bx * 128;
        Wb = Wq; bias = bq; outp = nullptr; scale = 1.0f;
    }

    // staging: A = 1 gld16/thread (64 rows x 4 slots); B = 2 gld16/thread
    const int srow = tid >> 2;          // 0..63
    const int scol = (tid & 3) * 8;
    const short* Asrc  = A  + (size_t)(m0 + srow) * HH + scol;
    const short* Bsrc0 = Wb + (size_t)(n0 + srow) * HH + scol;
    const short* Bsrc1 = Wb + (size_t)(n0 + 64 + srow) * HH + scol;
    short* Ald  = As + w*512;           // wave-uniform bases
    short* Bld0 = Bs + w*512;
    short* Bld1 = Bs + 2048 + w*512;

    f4v acc[2][4];
    #pragma unroll
    for (int i = 0; i < 2; i++)
        #pragma unroll
        for (int j = 0; j < 4; j++) acc[i][j] = (f4v){0.f,0.f,0.f,0.f};

    for (int kt = 0; kt < HH/32; ++kt) {
        const int k0 = kt * 32;
        gld16(Asrc  + k0, Ald);
        gld16(Bsrc0 + k0, Bld0);
        gld16(Bsrc1 + k0, Bld1);
        __syncthreads();

        s8v af[2], bf[4];
        #pragma unroll
        for (int mi = 0; mi < 2; mi++)
            af[mi] = *(const s8v*)(As + (wr*32 + mi*16 + r)*32 + g*8);
        #pragma unroll
        for (int ni = 0; ni < 4; ni++)
            bf[ni] = *(const s8v*)(Bs + (wc*64 + ni*16 + r)*32 + g*8);
        __builtin_amdgcn_s_setprio(1);
        #pragma unroll
        for (int mi = 0; mi < 2; mi++)
            #pragma unroll
            for (int ni = 0; ni < 4; ni++)
                acc[mi][ni] = __builtin_amdgcn_mfma_f32_16x16x32_bf16(af[mi], bf[ni], acc[mi][ni], 0, 0, 0);
        __builtin_amdgcn_s_setprio(0);
        __syncthreads();
    }

    if (EPI == 0) {
        if (seg < 2) {
            #pragma unroll
            for (int mi = 0; mi < 2; mi++) {
                #pragma unroll
                for (int j = 0; j < 4; j++) {
                    const int m = m0 + wr*32 + mi*16 + 4*g + j;
                    const int bb = m >> 11;
                    const int s  = m & 2047;
                    #pragma unroll
                    for (int ni = 0; ni < 4; ni++) {
                        const int n = n0 + wc*64 + ni*16 + r;
                        const int h = n >> 6;
                        const int d = n & 63;
                        outp[((size_t)((bb*NHEADS + h)*SEQ) + s)*HDIM + d] =
                            f2bf((acc[mi][ni][j] + bias[n]) * scale);
                    }
                }
            }
        } else {
            // V^T direct, k-permuted columns: 4 contiguous s stay contiguous
            #pragma unroll
            for (int mi = 0; mi < 2; mi++) {
                const int m  = m0 + wr*32 + mi*16 + 4*g;   // 4-aligned
                const int bb = m >> 11;
                const int s  = m & 2047;
                const int sp = kperm(s);                   // 4-aligned too
                #pragma unroll
                for (int ni = 0; ni < 4; ni++) {
                    const int n = n0 + wc*64 + ni*16 + r;
                    const int h = n >> 6;
                    const int d = n & 63;
                    s4v pk;
                    #pragma unroll
                    for (int j = 0; j < 4; j++)
                        pk[j] = f2bf(acc[mi][ni][j] + bias[n]);
                    *(s4v*)(outp + ((size_t)((bb*NHEADS + h)*HDIM) + d)*SEQ + sp) = pk;
                }
            }
        }
    } else {
        #pragma unroll
        for (int mi = 0; mi < 2; mi++) {
            #pragma unroll
            for (int j = 0; j < 4; j++) {
                const int m = m0 + wr*32 + mi*16 + 4*g + j;
                #pragma unroll
                for (int ni = 0; ni < 4; ni++) {
                    const int n = n0 + wc*64 + ni*16 + r;
                    Fo[(size_t)m*HH + n] = acc[mi][ni][j] + bias[n] + Xres[(size_t)m*HH + n];
                }
            }
        }
    }
}

// ---------------------------------------------------------------------------
// Flash attention, bf16 MFMA, 8 waves / 512 threads, KV-parity split.
// SWAPPED QK^T: mfma(kf, qf) -> lane (r,g) holds P[k][q=r]; k-slot
// permutation matched by V^T kperm layout and permuted fp32 mask LDS.
// Mask applied as MFMA C-INIT. PV A-fragment built in-register (cvt_pk).
// Fixed-max exp2 softmax; scalar per-lane l; parity merge at end.
// LDS 40 KB (K 2x8K, V 2x8K, mask-f32 8K); 128B rows, conflict-free.
// ---------------------------------------------------------------------------
#define NPAIR (SEQ/64)
__global__ __launch_bounds__(512, 4)
void attn_mfma(const short* __restrict__ Q, const short* __restrict__ K,
               const short* __restrict__ VT, const float* __restrict__ mask,
               short* __restrict__ CTX)
{
    // XCD swizzle: 768 blocks = 8 XCDs x 96
    const int wgid = (blockIdx.x & 7) * 96 + (blockIdx.x >> 3);
    const int qt = wgid & 31;
    const int bh = wgid >> 5;
    const int h  = bh % NHEADS;
    const int b  = bh / NHEADS;

    const size_t hb = (size_t)(b * NHEADS + h);
    const short* Qg  = Q  + hb * SEQ * HDIM;
    const short* Kg  = K  + hb * SEQ * HDIM;
    const short* VTg = VT + hb * HDIM * SEQ;   // k-permuted columns

    __shared__ __align__(16) char lds[40960];
    char* Kbase = lds;                    // [2 db][64 k-rows][128B]
    char* Vbase = lds + 16384;            // [2 db][64 d-rows][128B], k-pos order
    float* Mf   = (float*)(lds + 32768);  // [2048] fp32 madd, k-pos order

    const int tid  = threadIdx.x;
    const int w    = tid >> 6;
    const int grp  = w >> 2;
    const int wq   = w & 3;
    const int lane = tid & 63;
    const int g    = lane >> 4;
    const int r    = lane & 15;
    const int q0   = qt * 64;

    const short* qrow = Qg + (size_t)(q0 + wq*16 + r) * HDIM;
    const s8v qf0 = *(const s8v*)(qrow + 8*g);
    const s8v qf1 = *(const s8v*)(qrow + 8*g + 32);

    // one-time mask -> permuted fp32 LDS (512 threads x 4 entries)
    {
        float4 mv = *(const float4*)(mask + b*SEQ + tid*4);
        f4v md;
        md[0] = (mv.x - 1.0f) * (10000.0f * L2E);
        md[1] = (mv.y - 1.0f) * (10000.0f * L2E);
        md[2] = (mv.z - 1.0f) * (10000.0f * L2E);
        md[3] = (mv.w - 1.0f) * (10000.0f * L2E);
        *(f4v*)(Mf + kperm(tid*4)) = md;
    }

    f4v acc[4];
    #pragma unroll
    for (int t = 0; t < 4; t++) acc[t] = (f4v){0.f, 0.f, 0.f, 0.f};
    float lpart = 0.0f;

    const int srow = lane >> 3;
    const int scol = 8 * ((lane & 7) ^ srow);

    #define STAGE(PT, DB) do {                                                 \
        const int pk0 = (PT) * 64;                                             \
        char* kd = Kbase + (DB)*8192 + w*1024;                                 \
        gld16(Kg + (size_t)(pk0 + 8*w + srow)*HDIM + scol, kd);                \
        char* vd = Vbase + (DB)*8192 + w*1024;                                 \
        gld16(VTg + (size_t)(8*w + srow)*SEQ + pk0 + scol, vd);                \
    } while (0)

    STAGE(0, 0);
    __syncthreads();   // staging + mask preload

    for (int pt = 0; pt < NPAIR; ++pt) {
        const int db = pt & 1;
        if (pt + 1 < NPAIR) STAGE(pt + 1, db ^ 1);   // async, drained at barrier

        const char* Kc = Kbase + db*8192 + grp*4096; // 32 k-rows x 128B
        const char* Vc = Vbase + db*8192;            // 64 d-rows x 128B

        // madd C-init: slots (pt*64+grp*32+8g) + 0..3 (z0), +4..7 (z1)
        const float* mrow = Mf + pt*64 + grp*32 + 8*g;
        f4v z0 = *(const f4v*)(mrow);
        f4v z1 = *(const f4v*)(mrow + 4);

        // ---- swapped QK^T: z[jt][i] = S[k] + madd[k], k=4g+i+16jt ----
        __builtin_amdgcn_s_setprio(1);
        {
            const int sw = (r & 7) << 4;
            const char* kb0 = Kc + r * 128;          // jt=0 rows
            const char* kb1 = Kc + (16 + r) * 128;   // jt=1 rows
            s8v ka0 = *(const s8v*)(kb0 + ((16*g)      ^ sw));
            s8v ka1 = *(const s8v*)(kb0 + ((16*g + 64) ^ sw));
            s8v kc0 = *(const s8v*)(kb1 + ((16*g)      ^ sw));
            s8v kc1 = *(const s8v*)(kb1 + ((16*g + 64) ^ sw));
            z0 = __builtin_amdgcn_mfma_f32_16x16x32_bf16(ka0, qf0, z0, 0, 0, 0);
            z0 = __builtin_amdgcn_mfma_f32_16x16x32_bf16(ka1, qf1, z0, 0, 0, 0);
            z1 = __builtin_amdgcn_mfma_f32_16x16x32_bf16(kc0, qf0, z1, 0, 0, 0);
            z1 = __builtin_amdgcn_mfma_f32_16x16x32_bf16(kc1, qf1, z1, 0, 0, 0);
        }
        __builtin_amdgcn_s_setprio(0);

        #pragma unroll
        for (int i = 0; i < 4; i++) {
            z0[i] = EXP2(z0[i]);
            z1[i] = EXP2(z1[i]);
        }
        lpart += ((z0[0] + z0[1]) + (z0[2] + z0[3]))
               + ((z1[0] + z1[1]) + (z1[2] + z1[3]));

        // ---- PV A-fragment fully in-register (slot z = p[z>>2][z&3]) ----
        union { unsigned u[4]; s8v v; } pfu;
        pfu.u[0] = cvt_pk_bf16(z0[0], z0[1]);
        pfu.u[1] = cvt_pk_bf16(z0[2], z0[3]);
        pfu.u[2] = cvt_pk_bf16(z1[0], z1[1]);
        pfu.u[3] = cvt_pk_bf16(z1[2], z1[3]);
        const s8v pf = pfu.v;

        // ---- ctx += P @ V (k-extent 32, permuted positions grp*32+8g..) ----
        __builtin_amdgcn_s_setprio(1);
        #pragma unroll
        for (int t4 = 0; t4 < 4; t4++) {
            const int vrow = 16*t4 + r;
            s8v vf = *(const s8v*)(Vc + vrow*128 + ((16*(4*grp + g)) ^ ((r & 7) << 4)));
            acc[t4] = __builtin_amdgcn_mfma_f32_16x16x32_bf16(pf, vf, acc[t4], 0, 0, 0);
        }
        __builtin_amdgcn_s_setprio(0);

        __syncthreads();   // drains prefetch vmcnt; next pair ready, bufs free
    }

    // ---- reduce l across g-lanes (k-slices of this grp) ----
    lpart += __shfl_xor(lpart, 16);
    lpart += __shfl_xor(lpart, 32);   // all lanes with same r: l for q=wq*16+r

    // ---- merge parity partials (fixed-max => plain adds) ----
    float* lbuf = (float*)(lds + 20480);
    if (grp == 1) {
        float* mb = (float*)(lds + wq*5120 + lane*80);
        *(f4v*)(mb)      = acc[0];
        *(f4v*)(mb + 4)  = acc[1];
        *(f4v*)(mb + 8)  = acc[2];
        *(f4v*)(mb + 12) = acc[3];
        lbuf[wq*64 + lane] = lpart;
    }
    __syncthreads();
    if (grp == 0) {
        const float* mb = (const float*)(lds + wq*5120 + lane*80);
        acc[0] += *(const f4v*)(mb);
        acc[1] += *(const f4v*)(mb + 4);
        acc[2] += *(const f4v*)(mb + 8);
        acc[3] += *(const f4v*)(mb + 12);
        lpart  += lbuf[wq*64 + lane];

        #pragma unroll
        for (int i = 0; i < 4; i++) {
            const float invl = 1.0f / __shfl(lpart, 4*g + i);
            const size_t rowbase = ((size_t)(b*SEQ) + q0 + wq*16 + 4*g + i) * HH + h*HDIM;
            #pragma unroll
            for (int t4 = 0; t4 < 4; t4++)
                CTX[rowbase + 16*t4 + r] = f2bf(acc[t4][i] * invl);
        }
    }
    #undef STAGE
}

// ---------------------------------------------------------------------------
// In-place LayerNorm over rows of 768.
// ---------------------------------------------------------------------------
__global__ __launch_bounds__(256)
void ln_kernel(float* __restrict__ y, const float* __restrict__ gamma,
               const float* __restrict__ beta)
{
    const int row = blockIdx.x;
    float* p = y + (size_t)row * HH;
    const int tid = threadIdx.x;

    float v[3];
    float s = 0.f, ss = 0.f;
    #pragma unroll
    for (int i = 0; i < 3; i++) {
        float x = p[tid + i*256];
        v[i] = x;
        s += x;
        ss += x * x;
    }
    #pragma unroll
    for (int off = 32; off > 0; off >>= 1) {
        s  += __shfl_down(s,  off);
        ss += __shfl_down(ss, off);
    }
    __shared__ float sbuf[4], ssbuf[4];
    __shared__ float mu_s, rstd_s;
    const int wave = tid >> 6;
    if ((tid & 63) == 0) { sbuf[wave] = s; ssbuf[wave] = ss; }
    __syncthreads();
    if (tid == 0) {
        float S  = sbuf[0] + sbuf[1] + sbuf[2] + sbuf[3];
        float SS = ssbuf[0] + ssbuf[1] + ssbuf[2] + ssbuf[3];
        float mu = S * (1.0f / HH);
        float var = SS * (1.0f / HH) - mu * mu;
        mu_s = mu;
        rstd_s = rsqrtf(var + 1e-5f);
    }
    __syncthreads();
    const float mu = mu_s, rstd = rstd_s;
    #pragma unroll
    for (int i = 0; i < 3; i++) {
        const int c = tid + i*256;
        p[c] = (v[i] - mu) * rstd * gamma[c] + beta[c];
    }
}

// ---------------------------------------------------------------------------
extern "C" void kernel_launch(void* const* d_in, const int* in_sizes, int n_in,
                              void* d_out, int out_size, void* d_ws, size_t ws_size,
                              hipStream_t stream)
{
    const float* x     = (const float*)d_in[0];
    const float* mask  = (const float*)d_in[1];
    const float* Wq    = (const float*)d_in[2];
    const float* bq    = (const float*)d_in[3];
    const float* Wk    = (const float*)d_in[4];
    const float* bk    = (const float*)d_in[5];
    const float* Wv    = (const float*)d_in[6];
    const float* bv    = (const float*)d_in[7];
    const float* Wo    = (const float*)d_in[8];
    const float* bo    = (const float*)d_in[9];
    const float* gamma = (const float*)d_in[10];
    const float* beta  = (const float*)d_in[11];

    const size_t PER = (size_t)NB * NHEADS * SEQ * HDIM;
    const size_t WSZ = (size_t)HH * HH;
    short* wsS  = (short*)d_ws;
    short* Xb   = wsS;          // dead after QKV GEMM -> reused as CTXb
    short* Wqb  = wsS + PER;
    short* Wkb  = Wqb + WSZ;
    short* Wvb  = Wkb + WSZ;
    short* Wob  = Wvb + WSZ;
    short* Qb   = Wob + WSZ;
    short* Kb   = Qb + PER;
    short* VTb  = Kb + PER;     // k-permuted V^T written directly by the GEMM
    short* CTXb = Xb;
    float* out  = (float*)d_out;

    cvt_kernel<<<2688, 256, 0, stream>>>(x, Xb, Wq, Wqb, Wk, Wkb, Wv, Wvb, Wo, Wob);

    gemm_mfma<0><<<1152, 256, 0, stream>>>(
        Xb, Wqb, Wkb, Wvb, bq, bk, bv, Qb, Kb, VTb, nullptr, nullptr);

    attn_mfma<<<768, 512, 0, stream>>>(Qb, Kb, VTb, mask, CTXb);

    gemm_mfma<1><<<384, 256, 0, stream>>>(
        CTXb, Wob, nullptr, nullptr, bo, nullptr, nullptr,
        nullptr, nullptr, nullptr, x, out);

    ln_kernel<<<NB*SEQ, 256, 0, stream>>>(out, gamma, beta);
}